// Round 13
// baseline (1732.263 us; speedup 1.0000x reference)
//
#include <hip/hip_runtime.h>
#include <hip/hip_bf16.h>

// MobiusCollapseLayer: B=4,S=2048,D=1024,P=9,M=256, 3 twists. N=8192 tokens.
// Round 13: heavy GEMMs -> v_mfma_f32_32x32x16_bf16 (mgemm32): half the MFMA
// instructions, +20% matrix-pipe rate. LDS layout [m][half][row][8] = zero
// bank conflicts by construction. Everything else identical to r12.
typedef unsigned short u16;
typedef short bf16x8 __attribute__((ext_vector_type(8)));
typedef float f32x4 __attribute__((ext_vector_type(4)));
typedef float f32x16 __attribute__((ext_vector_type(16)));

constexpr int Dd = 1024, Pp = 9, Mm = 256, Nn = 8192, Kc = 2304;
constexpr int CAP = 4096;
constexpr float EPSf = 1e-6f;

__device__ __forceinline__ float bf2f(u16 u) {
    union { unsigned int u; float f; } v; v.u = ((unsigned int)u) << 16; return v.f;
}
__device__ __forceinline__ u16 f2bf(float f) {
    union { float f; unsigned int u; } v; v.f = f;
    unsigned int r = (v.u + 0x7FFFu + ((v.u >> 16) & 1u)) >> 16; return (u16)r;
}
__device__ __forceinline__ void split2(float v, u16& h, u16& l) {
    h = f2bf(v); l = f2bf(v - bf2f(h));
}
__device__ __forceinline__ void gld16(u16* lds, const u16* g) {
    __builtin_amdgcn_global_load_lds(
        (const __attribute__((address_space(1))) unsigned int*)g,
        (__attribute__((address_space(3))) unsigned int*)lds, 16, 0, 0);
}

// ---------------- weight prep ----------------
__global__ void rotcopy_k(const float* __restrict__ src, float* __restrict__ dst,
                          int R, int C, const float* __restrict__ theta, int Pb)
{
    long total = (long)Pb * R * C;
    long idx = (long)blockIdx.x * 256 + threadIdx.x;
    if (idx >= total) return;
    int c = (int)(idx % C);
    long rp = idx / C;
    int r = (int)(rp % R);
    int pb = (int)(rp / R);
    float th = theta[pb];
    const float* s = src + ((long)pb * R + r) * C;
    float v;
    if (c == 0)      v = s[0] * cosf(th) - s[1] * sinf(th);
    else if (c == 1) v = s[0] * sinf(th) + s[1] * cosf(th);
    else             v = s[c];
    dst[idx] = v;
}

__global__ void splitW1_k(const float* __restrict__ W1, const float* __restrict__ th,
                          u16* __restrict__ h, u16* __restrict__ l)
{
    int idx = blockIdx.x * 256 + threadIdx.x;
    if (idx >= 256 * 2048) return;
    int k = idx & 2047, n = idx >> 11;
    float v;
    if (n == 0)      v = W1[(long)k * 256 + 0] * cosf(th[0]) - W1[(long)k * 256 + 1] * sinf(th[0]);
    else if (n == 1) v = W1[(long)k * 256 + 0] * sinf(th[0]) + W1[(long)k * 256 + 1] * cosf(th[0]);
    else             v = W1[(long)k * 256 + n];
    u16 hh, ll; split2(v, hh, ll); h[idx] = hh; l[idx] = ll;
}

__global__ void splitTWT_k(const float* __restrict__ tW, const float* __restrict__ th,
                           u16* __restrict__ h, u16* __restrict__ l)
{
    int idx = blockIdx.x * 256 + threadIdx.x;
    if (idx >= 1024 * 1024) return;
    int d = idx & 1023, e = idx >> 10;
    const float* s = tW + (long)e * 1024;
    float v;
    if (d == 0)      v = s[0] * cosf(th[0]) - s[1] * sinf(th[0]);
    else if (d == 1) v = s[0] * sinf(th[0]) + s[1] * cosf(th[0]);
    else             v = s[d];
    u16 hh, ll; split2(v, hh, ll); h[idx] = hh; l[idx] = ll;
}

__global__ void splitWa_k(const float* __restrict__ Wa, const float* __restrict__ tha,
                          u16* __restrict__ h, u16* __restrict__ l)
{
    int idx = blockIdx.x * 256 + threadIdx.x;
    if (idx >= Kc * 1024) return;
    int k = idx & 1023, n = idx >> 10;
    int p = n >> 8, m = n & 255;
    const float* s = Wa + ((long)p * 1024 + k) * 256;
    float v;
    if (m == 0)      v = s[0] * cosf(tha[p]) - s[1] * sinf(tha[p]);
    else if (m == 1) v = s[0] * sinf(tha[p]) + s[1] * cosf(tha[p]);
    else             v = s[m];
    u16 hh, ll; split2(v, hh, ll); h[idx] = hh; l[idx] = ll;
}

__global__ void splitWb_k(const float* __restrict__ Wb, const float* __restrict__ thb,
                          u16* __restrict__ h, u16* __restrict__ l)
{
    int idx = blockIdx.x * 256 + threadIdx.x;
    if (idx >= 1024 * Kc) return;
    int n = idx / Kc;              // d
    int k = idx - n * Kc;          // p*256+m
    int p = k >> 8, m = k & 255;
    const float* s = Wb + ((long)p * 256 + m) * 1024;
    float v;
    if (n == 0)      v = s[0] * cosf(thb[p]) - s[1] * sinf(thb[p]);
    else if (n == 1) v = s[0] * sinf(thb[p]) + s[1] * cosf(thb[p]);
    else             v = s[n];
    u16 hh, ll; split2(v, hh, ll); h[idx] = hh; l[idx] = ll;
}

__global__ void bac2_k(const float* __restrict__ bac, const float* __restrict__ tbr,
                       const u16* __restrict__ Wath, const u16* __restrict__ Watl,
                       float* __restrict__ bac2)
{
    __shared__ float sb[256];
    int pm = blockIdx.x;
    int t = threadIdx.x;
    float s = 0.f;
    for (int d = t; d < 1024; d += 256) {
        long o = (long)pm * 1024 + d;
        s += tbr[d] * (bf2f(Wath[o]) + bf2f(Watl[o]));
    }
    sb[t] = s; __syncthreads();
    for (int st = 128; st >= 1; st >>= 1) {
        if (t < st) sb[t] += sb[t + st];
        __syncthreads();
    }
    if (t == 0) bac2[pm] = bac[pm] + sb[0];
}

__global__ void hp0_k(const u16* __restrict__ zxah, const u16* __restrict__ zxal,
                      const float* __restrict__ rw,
                      u16* __restrict__ hph, u16* __restrict__ hpl)
{
    int idx = blockIdx.x * 256 + threadIdx.x;
    if (idx >= Nn * Kc / 4) return;
    int c4 = idx % (Kc / 4);
    int n  = idx / (Kc / 4);
    float w = rw[(long)n * Pp + (c4 >> 6)];
    ushort4 zh = ((const ushort4*)zxah)[idx], zl = ((const ushort4*)zxal)[idx];
    ushort4 h4, l4;
    split2((bf2f(zh.x) + bf2f(zl.x)) * w, h4.x, l4.x);
    split2((bf2f(zh.y) + bf2f(zl.y)) * w, h4.y, l4.y);
    split2((bf2f(zh.z) + bf2f(zl.z)) * w, h4.z, l4.z);
    split2((bf2f(zh.w) + bf2f(zl.w)) * w, h4.w, l4.w);
    ((ushort4*)hph)[idx] = h4; ((ushort4*)hpl)[idx] = l4;
}

// ---------------- neighbor mixer -> split bf16 ----------------
__global__ void mixer_k(const float* __restrict__ x, const float* __restrict__ mw,
                        u16* __restrict__ xmh, u16* __restrict__ xml)
{
    int idx = blockIdx.x * 256 + threadIdx.x;
    if (idx >= Nn * Dd / 4) return;
    int d4 = idx & (Dd / 4 - 1);
    int n = idx >> 8;
    int s = n & 2047;
    const float4* x4 = (const float4*)x;
    const float4* w4 = (const float4*)mw;
    float4 xc = x4[idx];
    float4 w0 = w4[d4], w1 = w4[(Dd / 4) + d4], w2 = w4[2 * (Dd / 4) + d4];
    float o[4];
    o[0] = xc.x * w0.x; o[1] = xc.y * w0.y; o[2] = xc.z * w0.z; o[3] = xc.w * w0.w;
    if (s > 0) {
        float4 xl = x4[idx - Dd / 4];
        o[0] += xl.x * w1.x; o[1] += xl.y * w1.y; o[2] += xl.z * w1.z; o[3] += xl.w * w1.w;
    }
    if (s < 2047) {
        float4 xr = x4[idx + Dd / 4];
        o[0] += xr.x * w2.x; o[1] += xr.y * w2.y; o[2] += xr.z * w2.z; o[3] += xr.w * w2.w;
    }
    ushort4 h4, l4;
    split2(o[0], h4.x, l4.x); split2(o[1], h4.y, l4.y);
    split2(o[2], h4.z, l4.z); split2(o[3], h4.w, l4.w);
    ((ushort4*)xmh)[idx] = h4; ((ushort4*)xml)[idx] = l4;
}

__global__ void tanh_k(const float* __restrict__ a, float* __restrict__ o, int total)
{
    int idx = blockIdx.x * 256 + threadIdx.x;
    if (idx < total) o[idx] = tanhf(a[idx]);
}

// ============ mgemm32: 128x128 tile, 4 waves, 32x32x16 MFMA, dbuf, vmcnt(8) ====
// LDS per operand-half: [m(2)][q(2)][row(128)][8] u16 (4096 u16 = 8KB).
// EPI 5: Cf = acc + sum_p rwv*bbr             (stage B)
// EPI 6: split: acc (+bias if non-null)       (Wfat, zxa)
// EPI 7: split: (acc + CIsplit) * rw[r][c>>8] (stage A')
template<int EPI>
__global__ __launch_bounds__(256, 2) void mgemm32(
    const u16* __restrict__ Agh, const u16* __restrict__ Agl, int lda,
    const u16* __restrict__ Bgh, const u16* __restrict__ Bgl, int ldb,
    int K,
    float* __restrict__ Cf, u16* __restrict__ Coh, u16* __restrict__ Col, int ldc,
    const u16* __restrict__ CIh, const u16* __restrict__ CIl,
    const float* __restrict__ bias,
    const float* __restrict__ rwv,
    const float* __restrict__ bbrv)
{
    __shared__ u16 smem[2][16384];              // Ah|Al|Bh|Bl, 8KB each
    const int tid = threadIdx.x, wave = tid >> 6, lane = tid & 63;
    const int nwg = gridDim.x * gridDim.y;
    const int flat = blockIdx.y * gridDim.x + blockIdx.x;
    const int qx = nwg >> 3;
    const int l_ = (flat & 7) * qx + (flat >> 3);
    const int r0 = (l_ / gridDim.x) * 128, c0 = (l_ % gridDim.x) * 128;
    const int q5 = lane >> 5, l31 = lane & 31;
    const int arow0 = (wave >> 1) * 64, bcol0 = (wave & 1) * 64;
    // staging decode (slot = s*256 + tid -> m, half, row); wave-uniform LDS base
    const int s0 = tid >> 8, sm0 = (tid >> 7) & 1;   // unused helpers (kept simple below)

    f32x16 acc[2][2] = {};

    auto STAGE = [&](int buf, int k0) {
        u16* base = &smem[buf][0];
#pragma unroll
        for (int s = 0; s < 2; ++s) {
            const int slot = s * 256 + tid;
            const int m = slot >> 8, hh = (slot >> 7) & 1, row = slot & 127;
            const int ub = (s * 256 + wave * 64) * 8;       // wave-uniform
            const int koff = k0 + m * 16 + hh * 8;
            const long ga = (long)(r0 + row) * lda + koff;
            const long gb = (long)(c0 + row) * ldb + koff;
            gld16(base + ub,         Agh + ga);
            gld16(base + 4096 + ub,  Agl + ga);
            gld16(base + 8192 + ub,  Bgh + gb);
            gld16(base + 12288 + ub, Bgl + gb);
        }
    };
    auto COMPUTE = [&](int buf) {
        u16* Ash = &smem[buf][0];
        u16* Asl = &smem[buf][4096];
        u16* Bsh = &smem[buf][8192];
        u16* Bsl = &smem[buf][12288];
#pragma unroll
        for (int m = 0; m < 2; ++m) {
            bf16x8 ah[2], al[2], bh[2], bl[2];
#pragma unroll
            for (int i = 0; i < 2; ++i) {
                int sa = ((m * 2 + q5) * 128 + arow0 + i * 32 + l31) * 8;
                ah[i] = *(const bf16x8*)&Ash[sa];
                al[i] = *(const bf16x8*)&Asl[sa];
                int sb = ((m * 2 + q5) * 128 + bcol0 + i * 32 + l31) * 8;
                bh[i] = *(const bf16x8*)&Bsh[sb];
                bl[i] = *(const bf16x8*)&Bsl[sb];
            }
#pragma unroll
            for (int j = 0; j < 2; ++j)
#pragma unroll
                for (int i = 0; i < 2; ++i) {
                    acc[i][j] = __builtin_amdgcn_mfma_f32_32x32x16_bf16(ah[i], bh[j], acc[i][j], 0, 0, 0);
                    acc[i][j] = __builtin_amdgcn_mfma_f32_32x32x16_bf16(ah[i], bl[j], acc[i][j], 0, 0, 0);
                    acc[i][j] = __builtin_amdgcn_mfma_f32_32x32x16_bf16(al[i], bh[j], acc[i][j], 0, 0, 0);
                }
        }
    };

    const int NT = K / 32;
    STAGE(0, 0);
#pragma unroll 1
    for (int t = 0; t < NT; t += 2) {
        STAGE(1, (t + 1) * 32);
        asm volatile("s_waitcnt vmcnt(8)" ::: "memory");
        __builtin_amdgcn_sched_barrier(0);
        __builtin_amdgcn_s_barrier();
        __builtin_amdgcn_sched_barrier(0);
        COMPUTE(0);
        __builtin_amdgcn_sched_barrier(0);
        __builtin_amdgcn_s_barrier();
        __builtin_amdgcn_sched_barrier(0);
        if (t + 2 < NT) {
            STAGE(0, (t + 2) * 32);
            asm volatile("s_waitcnt vmcnt(8)" ::: "memory");
        } else {
            asm volatile("s_waitcnt vmcnt(0)" ::: "memory");
        }
        __builtin_amdgcn_sched_barrier(0);
        __builtin_amdgcn_s_barrier();
        __builtin_amdgcn_sched_barrier(0);
        COMPUTE(1);
        __builtin_amdgcn_sched_barrier(0);
        __builtin_amdgcn_s_barrier();
        __builtin_amdgcn_sched_barrier(0);
    }

    // C/D layout (32x32): col = lane&31, row = (reg&3) + 8*(reg>>2) + 4*(lane>>5)
#pragma unroll
    for (int i = 0; i < 2; ++i)
#pragma unroll
        for (int reg = 0; reg < 16; ++reg) {
            const int r = r0 + arow0 + i * 32 + (reg & 3) + 8 * (reg >> 2) + 4 * q5;
#pragma unroll
            for (int j = 0; j < 2; ++j) {
                const int c = c0 + bcol0 + j * 32 + l31;
                const long o = (long)r * ldc + c;
                float v = acc[i][j][reg];
                if constexpr (EPI == 5) {
#pragma unroll
                    for (int p = 0; p < 9; ++p) v += rwv[(long)r * 9 + p] * bbrv[p * 1024 + c];
                    Cf[o] = v;
                } else if constexpr (EPI == 6) {
                    if (bias) v += bias[c];
                    u16 h, l; split2(v, h, l); Coh[o] = h; Col[o] = l;
                } else {            // EPI 7
                    v = (v + bf2f(CIh[o]) + bf2f(CIl[o])) * rwv[(long)r * 9 + (c >> 8)];
                    u16 h, l; split2(v, h, l); Coh[o] = h; Col[o] = l;
                }
            }
        }
}

// ====== mgemmS: skinny 64x128 tile, 2 waves, 16x16x32, for obs/zx ======
template<int EPI>
__global__ __launch_bounds__(128, 2) void mgemmS(
    const u16* __restrict__ Agh, const u16* __restrict__ Agl, int lda,
    const u16* __restrict__ Bgh, const u16* __restrict__ Bgl, int ldb,
    int K,
    float* __restrict__ Cf, int ldc,
    const float* __restrict__ Cinit,
    const float* __restrict__ bias)
{
    __shared__ u16 smem[2][12288];
    const int tid = threadIdx.x, wave = tid >> 6, lane = tid & 63;
    const int nwg = gridDim.x * gridDim.y;
    const int flat = blockIdx.y * gridDim.x + blockIdx.x;
    const int q = nwg >> 3;
    const int l_ = (flat & 7) * q + (flat >> 3);
    const int r0 = (l_ / gridDim.x) * 64, c0 = (l_ % gridDim.x) * 128;
    const int srl = lane >> 2;
    const int ssl = ((lane & 3) ^ ((lane >> 3) & 3)) * 8;
    const int frl = lane & 15, kh = lane >> 4;
    const int sw  = (kh ^ ((frl >> 1) & 3)) * 8;
    const int w32 = wave * 32, w64 = wave * 64;

    f32x4 acc[4][4] = {};

    auto STAGE = [&](int buf, int k0) {
        u16* Ash = &smem[buf][0];
        u16* Asl = &smem[buf][2048];
        u16* Bsh = &smem[buf][4096];
        u16* Bsl = &smem[buf][8192];
        const long ga = (long)(r0 + w32 + srl) * lda + k0 + ssl;
        gld16(&Ash[w32 * 32],        Agh + ga);
        gld16(&Ash[(w32 + 16) * 32], Agh + ga + 16L * lda);
        gld16(&Asl[w32 * 32],        Agl + ga);
        gld16(&Asl[(w32 + 16) * 32], Agl + ga + 16L * lda);
        const long gb = (long)(c0 + w64 + srl) * ldb + k0 + ssl;
        gld16(&Bsh[w64 * 32],        Bgh + gb);
        gld16(&Bsh[(w64 + 16) * 32], Bgh + gb + 16L * ldb);
        gld16(&Bsh[(w64 + 32) * 32], Bgh + gb + 32L * ldb);
        gld16(&Bsh[(w64 + 48) * 32], Bgh + gb + 48L * ldb);
        gld16(&Bsl[w64 * 32],        Bgl + gb);
        gld16(&Bsl[(w64 + 16) * 32], Bgl + gb + 16L * ldb);
        gld16(&Bsl[(w64 + 32) * 32], Bgl + gb + 32L * ldb);
        gld16(&Bsl[(w64 + 48) * 32], Bgl + gb + 48L * ldb);
    };
    auto COMPUTE = [&](int buf) {
        u16* Ash = &smem[buf][0];
        u16* Asl = &smem[buf][2048];
        u16* Bsh = &smem[buf][4096];
        u16* Bsl = &smem[buf][8192];
        bf16x8 ah[4], al[4];
#pragma unroll
        for (int f = 0; f < 4; ++f) {
            int ao = (f * 16 + frl) * 32 + sw;
            ah[f] = *(const bf16x8*)&Ash[ao];
            al[f] = *(const bf16x8*)&Asl[ao];
        }
#pragma unroll
        for (int j = 0; j < 4; ++j) {
            int bo = (w64 + j * 16 + frl) * 32 + sw;
            bf16x8 bh = *(const bf16x8*)&Bsh[bo];
            bf16x8 bl = *(const bf16x8*)&Bsl[bo];
#pragma unroll
            for (int i = 0; i < 4; ++i) {
                acc[i][j] = __builtin_amdgcn_mfma_f32_16x16x32_bf16(ah[i], bh, acc[i][j], 0, 0, 0);
                acc[i][j] = __builtin_amdgcn_mfma_f32_16x16x32_bf16(ah[i], bl, acc[i][j], 0, 0, 0);
                acc[i][j] = __builtin_amdgcn_mfma_f32_16x16x32_bf16(al[i], bh, acc[i][j], 0, 0, 0);
            }
        }
    };

    const int NT = K / 32;
    STAGE(0, 0);
#pragma unroll 1
    for (int t = 0; t < NT; t += 2) {
        STAGE(1, (t + 1) * 32);
        asm volatile("s_waitcnt vmcnt(12)" ::: "memory");
        __builtin_amdgcn_sched_barrier(0);
        __builtin_amdgcn_s_barrier();
        __builtin_amdgcn_sched_barrier(0);
        COMPUTE(0);
        __builtin_amdgcn_sched_barrier(0);
        __builtin_amdgcn_s_barrier();
        __builtin_amdgcn_sched_barrier(0);
        if (t + 2 < NT) {
            STAGE(0, (t + 2) * 32);
            asm volatile("s_waitcnt vmcnt(12)" ::: "memory");
        } else {
            asm volatile("s_waitcnt vmcnt(0)" ::: "memory");
        }
        __builtin_amdgcn_sched_barrier(0);
        __builtin_amdgcn_s_barrier();
        __builtin_amdgcn_sched_barrier(0);
        COMPUTE(1);
        __builtin_amdgcn_sched_barrier(0);
        __builtin_amdgcn_s_barrier();
        __builtin_amdgcn_sched_barrier(0);
    }

#pragma unroll
    for (int i = 0; i < 4; ++i)
#pragma unroll
        for (int reg = 0; reg < 4; ++reg) {
            const int r = r0 + i * 16 + kh * 4 + reg;
#pragma unroll
            for (int j = 0; j < 4; ++j) {
                const int c = c0 + w64 + j * 16 + frl;
                const long o = (long)r * ldc + c;
                float v = acc[i][j][reg];
                if constexpr (EPI == 0) Cf[o] = v + bias[c];
                else                    Cf[o] = tanhf(v + Cinit[o]);
            }
        }
}

// ====== final routing: bucketed K=256 GEMM with indirect rows (16x16) ======
__global__ void bucket_k(const int* __restrict__ pstar, int* __restrict__ cnt,
                         int* __restrict__ perm)
{
    int n = blockIdx.x * 256 + threadIdx.x;
    if (n >= Nn) return;
    int p = pstar[n];
    int slot = atomicAdd(&cnt[p], 1);
    if (slot < CAP) perm[p * CAP + slot] = n;
}

__global__ __launch_bounds__(256, 2) void mgemm_fin(
    const u16* __restrict__ hph, const u16* __restrict__ hpl,
    const u16* __restrict__ Wbth, const u16* __restrict__ Wbtl,
    const int* __restrict__ perm, const int* __restrict__ cnt,
    const float* __restrict__ rwS, const float* __restrict__ bbr,
    float* __restrict__ craw)
{
    __shared__ u16 smem[2][16384];
    const int tid = threadIdx.x, wave = tid >> 6, lane = tid & 63;
    const int p = blockIdx.y >> 5;
    const int rb0 = (blockIdx.y & 31) * 128;
    const int cntp = cnt[p];
    if (rb0 >= cntp) return;
    const int c0 = blockIdx.x * 128;
    const int pbase = p * 256;
    const int srl = lane >> 2;
    const int ssl = ((lane & 3) ^ ((lane >> 3) & 3)) * 8;
    const int frl = lane & 15, kh = lane >> 4;
    const int sw  = (kh ^ ((frl >> 1) & 3)) * 8;
    const int arow0 = (wave >> 1) * 64, bcol0 = (wave & 1) * 64;
    const int w32 = wave * 32;
    const int tok0 = perm[p * CAP + rb0 + w32 + srl];
    const int tok1 = perm[p * CAP + rb0 + w32 + 16 + srl];

    f32x4 acc[4][4] = {};

    auto STAGE = [&](int buf, int k0) {
        u16* base = &smem[buf][0];
        u16* As_h = base;        u16* As_l = base + 4096;
        u16* Bs_h = base + 8192; u16* Bs_l = base + 12288;
        const long ga0 = (long)tok0 * Kc + pbase + k0 + ssl;
        const long ga1 = (long)tok1 * Kc + pbase + k0 + ssl;
        gld16(&As_h[w32 * 32],        hph + ga0);
        gld16(&As_h[(w32 + 16) * 32], hph + ga1);
        gld16(&As_l[w32 * 32],        hpl + ga0);
        gld16(&As_l[(w32 + 16) * 32], hpl + ga1);
        const long gb0 = (long)(c0 + w32 + srl) * Kc + pbase + k0 + ssl;
        gld16(&Bs_h[w32 * 32],        Wbth + gb0);
        gld16(&Bs_h[(w32 + 16) * 32], Wbth + gb0 + 16L * Kc);
        gld16(&Bs_l[w32 * 32],        Wbtl + gb0);
        gld16(&Bs_l[(w32 + 16) * 32], Wbtl + gb0 + 16L * Kc);
    };
    auto COMPUTE = [&](int buf) {
        u16* base = &smem[buf][0];
        u16* As_h = base;        u16* As_l = base + 4096;
        u16* Bs_h = base + 8192; u16* Bs_l = base + 12288;
        bf16x8 ah[4], al[4];
#pragma unroll
        for (int f = 0; f < 4; ++f) {
            int ao = (arow0 + f * 16 + frl) * 32 + sw;
            ah[f] = *(const bf16x8*)&As_h[ao];
            al[f] = *(const bf16x8*)&As_l[ao];
        }
#pragma unroll
        for (int j = 0; j < 4; ++j) {
            int bo = (bcol0 + j * 16 + frl) * 32 + sw;
            bf16x8 bh = *(const bf16x8*)&Bs_h[bo];
            bf16x8 bl = *(const bf16x8*)&Bs_l[bo];
#pragma unroll
            for (int i = 0; i < 4; ++i) {
                acc[i][j] = __builtin_amdgcn_mfma_f32_16x16x32_bf16(ah[i], bh, acc[i][j], 0, 0, 0);
                acc[i][j] = __builtin_amdgcn_mfma_f32_16x16x32_bf16(ah[i], bl, acc[i][j], 0, 0, 0);
                acc[i][j] = __builtin_amdgcn_mfma_f32_16x16x32_bf16(al[i], bh, acc[i][j], 0, 0, 0);
            }
        }
    };

    STAGE(0, 0);
#pragma unroll 1
    for (int t = 0; t < 8; t += 2) {
        STAGE(1, (t + 1) * 32);
        asm volatile("s_waitcnt vmcnt(8)" ::: "memory");
        __builtin_amdgcn_sched_barrier(0);
        __builtin_amdgcn_s_barrier();
        __builtin_amdgcn_sched_barrier(0);
        COMPUTE(0);
        __builtin_amdgcn_sched_barrier(0);
        __builtin_amdgcn_s_barrier();
        __builtin_amdgcn_sched_barrier(0);
        if (t + 2 < 8) {
            STAGE(0, (t + 2) * 32);
            asm volatile("s_waitcnt vmcnt(8)" ::: "memory");
        } else {
            asm volatile("s_waitcnt vmcnt(0)" ::: "memory");
        }
        __builtin_amdgcn_sched_barrier(0);
        __builtin_amdgcn_s_barrier();
        __builtin_amdgcn_sched_barrier(0);
        COMPUTE(1);
        __builtin_amdgcn_sched_barrier(0);
        __builtin_amdgcn_s_barrier();
        __builtin_amdgcn_sched_barrier(0);
    }

#pragma unroll
    for (int i = 0; i < 4; ++i)
#pragma unroll
        for (int reg = 0; reg < 4; ++reg) {
            const int gr = rb0 + arow0 + i * 16 + kh * 4 + reg;
            if (gr < cntp) {
                const int tokr = perm[p * CAP + gr];
                const float w = 1.f / rwS[(long)tokr * Pp + p];
#pragma unroll
                for (int j = 0; j < 4; ++j) {
                    const int c = c0 + bcol0 + j * 16 + frl;
                    craw[(long)tokr * Dd + c] = acc[i][j][reg] * w + bbr[p * 1024 + c];
                }
            }
        }
}

// ---------------- logits + softmax / hard-argmax ----------------
__global__ void logits_k(const float* __restrict__ h, const float* __restrict__ W2r,
                         const float* __restrict__ b2r, const float* __restrict__ gum,
                         float* __restrict__ rwA, int* __restrict__ pstar, int hard)
{
    __shared__ float hs[Mm];
    __shared__ float lg[16];
    int n = blockIdx.x;
    for (int i = threadIdx.x; i < Mm; i += 64) hs[i] = h[(long)n * Mm + i];
    __syncthreads();
    if (threadIdx.x < Pp) {
        int p = threadIdx.x;
        float acc = b2r[p];
        for (int m = 0; m < Mm; ++m) acc += hs[m] * W2r[m * Pp + p];
        lg[p] = acc + gum[(long)n * Pp + p];
    }
    __syncthreads();
    if (threadIdx.x == 0) {
        float mx = lg[0]; int am = 0;
#pragma unroll
        for (int p = 1; p < Pp; ++p) if (lg[p] > mx) { mx = lg[p]; am = p; }
        if (hard) {
            pstar[n] = am;
        } else {
            float e[Pp]; float ssum = 0.f;
#pragma unroll
            for (int p = 0; p < Pp; ++p) { e[p] = expf(lg[p] - mx); ssum += e[p]; }
#pragma unroll
            for (int p = 0; p < Pp; ++p) rwA[(long)n * Pp + p] = e[p] / ssum;
        }
    }
}

// ---------------- mod-phase RMS norm (group = d % 7) ----------------
template<int INSPLIT, int OUTSPLIT>
__global__ void norm_k(const float* __restrict__ in,
                       const u16* __restrict__ inh, const u16* __restrict__ inl,
                       const float* __restrict__ add, const float* __restrict__ g,
                       float* __restrict__ outf, u16* __restrict__ oh, u16* __restrict__ ol)
{
    __shared__ float sb[256][8];
    __shared__ float dn[8];
    int n = blockIdx.x;
    int t = threadIdx.x;
    float v[4];
#pragma unroll
    for (int j = 0; j < 7; ++j) sb[t][j] = 0.f;
#pragma unroll
    for (int i = 0; i < 4; ++i) {
        int d = t + i * 256;
        long o = (long)n * Dd + d;
        float xv = INSPLIT ? (bf2f(inh[o]) + bf2f(inl[o])) : in[o];
        if (add) xv += add[o];
        v[i] = xv;
        sb[t][d % 7] += xv * xv;
    }
    __syncthreads();
    for (int st = 128; st >= 1; st >>= 1) {
        if (t < st) {
#pragma unroll
            for (int j = 0; j < 7; ++j) sb[t][j] += sb[t + st][j];
        }
        __syncthreads();
    }
    if (t < 7) {
        const float cnt = (t < 2) ? 147.f : 146.f;
        dn[t] = 1.f / sqrtf(sb[0][t] / cnt + EPSf);
    }
    __syncthreads();
#pragma unroll
    for (int i = 0; i < 4; ++i) {
        int d = t + i * 256;
        long o = (long)n * Dd + d;
        float ov = v[i] * dn[d % 7] * g[d];
        if (OUTSPLIT) { u16 h, l; split2(ov, h, l); oh[o] = h; ol[o] = l; }
        else outf[o] = ov;
    }
}

static inline int cdiv(long a, long b) { return (int)((a + b - 1) / b); }
static inline size_t al256(size_t b) { return (b + 255) & ~(size_t)255; }

extern "C" void kernel_launch(void* const* d_in, const int* in_sizes, int n_in,
                              void* d_out, int out_size, void* d_ws, size_t ws_size,
                              hipStream_t stream)
{
    const float* x    = (const float*)d_in[0];
    const float* gum  = (const float*)d_in[1];
    const float* mw   = (const float*)d_in[2];
    const float* W1   = (const float*)d_in[3];
    const float* b1   = (const float*)d_in[4];
    const float* th1  = (const float*)d_in[5];
    const float* W2   = (const float*)d_in[6];
    const float* b2   = (const float*)d_in[7];
    const float* th2  = (const float*)d_in[8];
    const float* Wa   = (const float*)d_in[9];
    const float* ba   = (const float*)d_in[10];
    const float* tha  = (const float*)d_in[11];
    const float* Wb   = (const float*)d_in[12];
    const float* bbv  = (const float*)d_in[13];
    const float* thb  = (const float*)d_in[14];
    const float* tW   = (const float*)d_in[15];
    const float* tb   = (const float*)d_in[16];
    const float* tth  = (const float*)d_in[17];
    const float* gnorm = (const float*)d_in[18];

    char* cur = (char*)d_ws;
    auto alloc = [&](size_t bytes) -> void* { void* r = cur; cur += al256(bytes); return r; };

    void* region = alloc((size_t)Nn * Dd * 4);   // craw f32 == hbuf f32 == xm split
    float* zx   = (float*)alloc((size_t)Nn * Mm * 4);
    float* rwS  = (float*)alloc((size_t)Nn * Pp * 4);
    u16* colh = (u16*)alloc((size_t)Nn * Dd * 2);
    u16* coll = (u16*)alloc((size_t)Nn * Dd * 2);
    u16* hph  = (u16*)alloc((size_t)Nn * Kc * 2);
    u16* hpl  = (u16*)alloc((size_t)Nn * Kc * 2);
    u16* W1th = (u16*)alloc(256 * 2048 * 2);
    u16* W1tl = (u16*)alloc(256 * 2048 * 2);
    u16* Wath = (u16*)alloc((size_t)Kc * 1024 * 2);
    u16* Watl = (u16*)alloc((size_t)Kc * 1024 * 2);
    u16* Wbth = (u16*)alloc((size_t)1024 * Kc * 2);
    u16* Wbtl = (u16*)alloc((size_t)1024 * Kc * 2);
    u16* zxah  = (u16*)alloc((size_t)Nn * Kc * 2);
    u16* zxal  = (u16*)alloc((size_t)Nn * Kc * 2);
    u16* tWtTh = (u16*)alloc((size_t)1024 * 1024 * 2);
    u16* tWtTl = (u16*)alloc((size_t)1024 * 1024 * 2);
    u16* Wfath = (u16*)alloc((size_t)Kc * 1024 * 2);
    u16* Wfatl = (u16*)alloc((size_t)Kc * 1024 * 2);
    float* W2r  = (float*)alloc(256 * 9 * 4);
    float* b1r  = (float*)alloc(256 * 4);
    float* b2r  = (float*)alloc(64);
    float* bac  = (float*)alloc(Kc * 4);
    float* bac2 = (float*)alloc(Kc * 4);
    float* bbr  = (float*)alloc(Pp * 1024 * 4);
    float* tbr  = (float*)alloc(1024 * 4);
    int* pstar = (int*)alloc(Nn * 4);
    int* perm  = (int*)alloc((size_t)Pp * CAP * 4);
    int* cnt   = (int*)alloc(Pp * 4);
    if ((size_t)(cur - (char*)d_ws) > ws_size) return;

    float* hbuf = (float*)region;
    float* craw = (float*)region;
    u16* xmh = (u16*)region;
    u16* xml = xmh + (size_t)Nn * Dd;
    float* out0 = (float*)d_out;
    float* out1 = out0 + (long)Nn * Dd;

    // ---- prep ----
    splitW1_k<<<2048, 256, 0, stream>>>(W1, th1, W1th, W1tl);
    splitWa_k<<<cdiv((long)Kc * 1024, 256), 256, 0, stream>>>(Wa, tha, Wath, Watl);
    splitWb_k<<<cdiv((long)1024 * Kc, 256), 256, 0, stream>>>(Wb, thb, Wbth, Wbtl);
    rotcopy_k<<<cdiv(256L * 9, 256), 256, 0, stream>>>(W2, W2r, 256, 9, th2, 1);
    rotcopy_k<<<1, 256, 0, stream>>>(b1, b1r, 1, 256, th1, 1);
    rotcopy_k<<<1, 256, 0, stream>>>(b2, b2r, 1, 9, th2, 1);
    rotcopy_k<<<cdiv((long)Pp * Mm, 256), 256, 0, stream>>>(ba, bac, 1, 256, tha, 9);
    rotcopy_k<<<cdiv((long)Pp * 1024, 256), 256, 0, stream>>>(bbv, bbr, 1, 1024, thb, 9);
    rotcopy_k<<<cdiv(1024L, 256), 256, 0, stream>>>(tb, tbr, 1, 1024, tth, 1);
    splitTWT_k<<<4096, 256, 0, stream>>>(tW, tth, tWtTh, tWtTl);
    hipMemsetAsync(perm, 0, (size_t)Pp * CAP * 4, stream);
    hipMemsetAsync(cnt, 0, Pp * 4, stream);

    // Wfat[pm,e] = sum_d Wat[pm,d] * tWtT[e,d]
    mgemm32<6><<<dim3(8, 18), 256, 0, stream>>>(
        Wath, Watl, 1024, tWtTh, tWtTl, 1024, 1024,
        nullptr, Wfath, Wfatl, 1024, nullptr, nullptr, nullptr, nullptr, nullptr);
    bac2_k<<<Kc, 256, 0, stream>>>(bac, tbr, Wath, Watl, bac2);

    mixer_k<<<Nn * Dd / 4 / 256, 256, 0, stream>>>(x, mw, xmh, xml);
    // zx = xm @ W1_top + b1r  (skinny, 256 blocks)
    mgemmS<0><<<dim3(2, 128), 128, 0, stream>>>(
        xmh, xml, 1024, W1th, W1tl, 2048, 1024, zx, 256, nullptr, b1r);
    // zxa = xm @ Wat + bac2   (split out) — before tanh clobbers xm
    mgemm32<6><<<dim3(18, 64), 256, 0, stream>>>(
        xmh, xml, 1024, Wath, Watl, 1024, 1024,
        nullptr, zxah, zxal, Kc, nullptr, nullptr, bac2, nullptr, nullptr);

    for (int t = 0; t < 3; ++t) {
        if (t == 0) {
            tanh_k<<<cdiv((long)Nn * Mm, 256), 256, 0, stream>>>(zx, hbuf, Nn * Mm);
        } else {
            mgemmS<1><<<dim3(2, 128), 128, 0, stream>>>(
                colh, coll, 1024, W1th + 1024, W1tl + 1024, 2048, 1024,
                hbuf, 256, zx, nullptr);
        }
        logits_k<<<Nn, 64, 0, stream>>>(hbuf, W2r, b2r, gum + (long)t * Nn * Pp,
                                        rwS, nullptr, 0);
        if (t == 0) {
            hp0_k<<<cdiv((long)Nn * Kc / 4, 256), 256, 0, stream>>>(zxah, zxal, rwS, hph, hpl);
        } else {
            // hp = (zxa + col @ Wfat) * rw
            mgemm32<7><<<dim3(18, 64), 256, 0, stream>>>(
                colh, coll, 1024, Wfath, Wfatl, 1024, 1024,
                nullptr, hph, hpl, Kc, zxah, zxal, nullptr, rwS, nullptr);
        }
        // craw = hp @ Wbt + sum_p rw_p bbr_p
        mgemm32<5><<<dim3(8, 64), 256, 0, stream>>>(
            hph, hpl, Kc, Wbth, Wbtl, Kc, Kc,
            craw, nullptr, nullptr, 1024, nullptr, nullptr, nullptr, rwS, bbr);
        norm_k<0, 1><<<Nn, 256, 0, stream>>>(craw, nullptr, nullptr, nullptr, gnorm,
                                             nullptr, colh, coll);
    }

    // ---- final hard routing (bucketed) ----
    mgemmS<1><<<dim3(2, 128), 128, 0, stream>>>(
        colh, coll, 1024, W1th + 1024, W1tl + 1024, 2048, 1024,
        hbuf, 256, zx, nullptr);
    logits_k<<<Nn, 64, 0, stream>>>(hbuf, W2r, b2r, gum + 3L * Nn * Pp,
                                    nullptr, pstar, 1);
    bucket_k<<<32, 256, 0, stream>>>(pstar, cnt, perm);
    mgemm_fin<<<dim3(8, Pp * 32), 256, 0, stream>>>(
        hph, hpl, Wbth, Wbtl, perm, cnt, rwS, bbr, craw);
    // out0 = norm(x + fc_raw); out1 = norm(collapsed)
    norm_k<0, 0><<<Nn, 256, 0, stream>>>(craw, nullptr, nullptr, x, gnorm, out0, nullptr, nullptr);
    norm_k<1, 0><<<Nn, 256, 0, stream>>>(nullptr, colh, coll, nullptr, gnorm, out1, nullptr, nullptr);
}

// Round 14
// 1327.549 us; speedup vs baseline: 1.3049x; 1.3049x over previous
//
#include <hip/hip_runtime.h>
#include <hip/hip_bf16.h>

// MobiusCollapseLayer: B=4,S=2048,D=1024,P=9,M=256, 3 twists. N=8192 tokens.
// Round 14: revert heavy GEMMs to r12's 16x16 mgemm (r13's 32x32 broke global
// coalescing: FETCH 165->235MB). Add: norm_k LDS pad [256][9] (kills 16-way
// bank conflict), wave-parallel logits (8 lanes/p + shfl reduce).
typedef unsigned short u16;
typedef short bf16x8 __attribute__((ext_vector_type(8)));
typedef float f32x4 __attribute__((ext_vector_type(4)));

constexpr int Dd = 1024, Pp = 9, Mm = 256, Nn = 8192, Kc = 2304;
constexpr int CAP = 4096;
constexpr float EPSf = 1e-6f;

__device__ __forceinline__ float bf2f(u16 u) {
    union { unsigned int u; float f; } v; v.u = ((unsigned int)u) << 16; return v.f;
}
__device__ __forceinline__ u16 f2bf(float f) {
    union { float f; unsigned int u; } v; v.f = f;
    unsigned int r = (v.u + 0x7FFFu + ((v.u >> 16) & 1u)) >> 16; return (u16)r;
}
__device__ __forceinline__ void split2(float v, u16& h, u16& l) {
    h = f2bf(v); l = f2bf(v - bf2f(h));
}
__device__ __forceinline__ void gld16(u16* lds, const u16* g) {
    __builtin_amdgcn_global_load_lds(
        (const __attribute__((address_space(1))) unsigned int*)g,
        (__attribute__((address_space(3))) unsigned int*)lds, 16, 0, 0);
}

// ---------------- weight prep ----------------
__global__ void rotcopy_k(const float* __restrict__ src, float* __restrict__ dst,
                          int R, int C, const float* __restrict__ theta, int Pb)
{
    long total = (long)Pb * R * C;
    long idx = (long)blockIdx.x * 256 + threadIdx.x;
    if (idx >= total) return;
    int c = (int)(idx % C);
    long rp = idx / C;
    int r = (int)(rp % R);
    int pb = (int)(rp / R);
    float th = theta[pb];
    const float* s = src + ((long)pb * R + r) * C;
    float v;
    if (c == 0)      v = s[0] * cosf(th) - s[1] * sinf(th);
    else if (c == 1) v = s[0] * sinf(th) + s[1] * cosf(th);
    else             v = s[c];
    dst[idx] = v;
}

__global__ void splitW1_k(const float* __restrict__ W1, const float* __restrict__ th,
                          u16* __restrict__ h, u16* __restrict__ l)
{
    int idx = blockIdx.x * 256 + threadIdx.x;
    if (idx >= 256 * 2048) return;
    int k = idx & 2047, n = idx >> 11;
    float v;
    if (n == 0)      v = W1[(long)k * 256 + 0] * cosf(th[0]) - W1[(long)k * 256 + 1] * sinf(th[0]);
    else if (n == 1) v = W1[(long)k * 256 + 0] * sinf(th[0]) + W1[(long)k * 256 + 1] * cosf(th[0]);
    else             v = W1[(long)k * 256 + n];
    u16 hh, ll; split2(v, hh, ll); h[idx] = hh; l[idx] = ll;
}

__global__ void splitTWT_k(const float* __restrict__ tW, const float* __restrict__ th,
                           u16* __restrict__ h, u16* __restrict__ l)
{
    int idx = blockIdx.x * 256 + threadIdx.x;
    if (idx >= 1024 * 1024) return;
    int d = idx & 1023, e = idx >> 10;
    const float* s = tW + (long)e * 1024;
    float v;
    if (d == 0)      v = s[0] * cosf(th[0]) - s[1] * sinf(th[0]);
    else if (d == 1) v = s[0] * sinf(th[0]) + s[1] * cosf(th[0]);
    else             v = s[d];
    u16 hh, ll; split2(v, hh, ll); h[idx] = hh; l[idx] = ll;
}

__global__ void splitWa_k(const float* __restrict__ Wa, const float* __restrict__ tha,
                          u16* __restrict__ h, u16* __restrict__ l)
{
    int idx = blockIdx.x * 256 + threadIdx.x;
    if (idx >= Kc * 1024) return;
    int k = idx & 1023, n = idx >> 10;
    int p = n >> 8, m = n & 255;
    const float* s = Wa + ((long)p * 1024 + k) * 256;
    float v;
    if (m == 0)      v = s[0] * cosf(tha[p]) - s[1] * sinf(tha[p]);
    else if (m == 1) v = s[0] * sinf(tha[p]) + s[1] * cosf(tha[p]);
    else             v = s[m];
    u16 hh, ll; split2(v, hh, ll); h[idx] = hh; l[idx] = ll;
}

__global__ void splitWb_k(const float* __restrict__ Wb, const float* __restrict__ thb,
                          u16* __restrict__ h, u16* __restrict__ l)
{
    int idx = blockIdx.x * 256 + threadIdx.x;
    if (idx >= 1024 * Kc) return;
    int n = idx / Kc;              // d
    int k = idx - n * Kc;          // p*256+m
    int p = k >> 8, m = k & 255;
    const float* s = Wb + ((long)p * 256 + m) * 1024;
    float v;
    if (n == 0)      v = s[0] * cosf(thb[p]) - s[1] * sinf(thb[p]);
    else if (n == 1) v = s[0] * sinf(thb[p]) + s[1] * cosf(thb[p]);
    else             v = s[n];
    u16 hh, ll; split2(v, hh, ll); h[idx] = hh; l[idx] = ll;
}

__global__ void bac2_k(const float* __restrict__ bac, const float* __restrict__ tbr,
                       const u16* __restrict__ Wath, const u16* __restrict__ Watl,
                       float* __restrict__ bac2)
{
    __shared__ float sb[256];
    int pm = blockIdx.x;
    int t = threadIdx.x;
    float s = 0.f;
    for (int d = t; d < 1024; d += 256) {
        long o = (long)pm * 1024 + d;
        s += tbr[d] * (bf2f(Wath[o]) + bf2f(Watl[o]));
    }
    sb[t] = s; __syncthreads();
    for (int st = 128; st >= 1; st >>= 1) {
        if (t < st) sb[t] += sb[t + st];
        __syncthreads();
    }
    if (t == 0) bac2[pm] = bac[pm] + sb[0];
}

__global__ void hp0_k(const u16* __restrict__ zxah, const u16* __restrict__ zxal,
                      const float* __restrict__ rw,
                      u16* __restrict__ hph, u16* __restrict__ hpl)
{
    int idx = blockIdx.x * 256 + threadIdx.x;
    if (idx >= Nn * Kc / 4) return;
    int c4 = idx % (Kc / 4);
    int n  = idx / (Kc / 4);
    float w = rw[(long)n * Pp + (c4 >> 6)];
    ushort4 zh = ((const ushort4*)zxah)[idx], zl = ((const ushort4*)zxal)[idx];
    ushort4 h4, l4;
    split2((bf2f(zh.x) + bf2f(zl.x)) * w, h4.x, l4.x);
    split2((bf2f(zh.y) + bf2f(zl.y)) * w, h4.y, l4.y);
    split2((bf2f(zh.z) + bf2f(zl.z)) * w, h4.z, l4.z);
    split2((bf2f(zh.w) + bf2f(zl.w)) * w, h4.w, l4.w);
    ((ushort4*)hph)[idx] = h4; ((ushort4*)hpl)[idx] = l4;
}

// ---------------- neighbor mixer -> split bf16 ----------------
__global__ void mixer_k(const float* __restrict__ x, const float* __restrict__ mw,
                        u16* __restrict__ xmh, u16* __restrict__ xml)
{
    int idx = blockIdx.x * 256 + threadIdx.x;
    if (idx >= Nn * Dd / 4) return;
    int d4 = idx & (Dd / 4 - 1);
    int n = idx >> 8;
    int s = n & 2047;
    const float4* x4 = (const float4*)x;
    const float4* w4 = (const float4*)mw;
    float4 xc = x4[idx];
    float4 w0 = w4[d4], w1 = w4[(Dd / 4) + d4], w2 = w4[2 * (Dd / 4) + d4];
    float o[4];
    o[0] = xc.x * w0.x; o[1] = xc.y * w0.y; o[2] = xc.z * w0.z; o[3] = xc.w * w0.w;
    if (s > 0) {
        float4 xl = x4[idx - Dd / 4];
        o[0] += xl.x * w1.x; o[1] += xl.y * w1.y; o[2] += xl.z * w1.z; o[3] += xl.w * w1.w;
    }
    if (s < 2047) {
        float4 xr = x4[idx + Dd / 4];
        o[0] += xr.x * w2.x; o[1] += xr.y * w2.y; o[2] += xr.z * w2.z; o[3] += xr.w * w2.w;
    }
    ushort4 h4, l4;
    split2(o[0], h4.x, l4.x); split2(o[1], h4.y, l4.y);
    split2(o[2], h4.z, l4.z); split2(o[3], h4.w, l4.w);
    ((ushort4*)xmh)[idx] = h4; ((ushort4*)xml)[idx] = l4;
}

__global__ void tanh_k(const float* __restrict__ a, float* __restrict__ o, int total)
{
    int idx = blockIdx.x * 256 + threadIdx.x;
    if (idx < total) o[idx] = tanhf(a[idx]);
}

// ============ mgemm (r5/r12 structure: 128x128, 4 waves, dbuf, vmcnt(8)) ======
// EPI 5: Cf = acc + sum_p rwv*bbr             (stage B)
// EPI 6: split: acc (+bias if non-null)       (Wfat, zxa)
// EPI 7: split: (acc + CIsplit) * rw[r][c>>8] (stage A')
template<int EPI>
__global__ __launch_bounds__(256, 2) void mgemm(
    const u16* __restrict__ Agh, const u16* __restrict__ Agl, int lda,
    const u16* __restrict__ Bgh, const u16* __restrict__ Bgl, int ldb,
    int K,
    float* __restrict__ Cf, u16* __restrict__ Coh, u16* __restrict__ Col, int ldc,
    const u16* __restrict__ CIh, const u16* __restrict__ CIl,
    const float* __restrict__ bias,
    const float* __restrict__ rwv,
    const float* __restrict__ bbrv)
{
    __shared__ u16 smem[2][16384];
    const int tid = threadIdx.x, wave = tid >> 6, lane = tid & 63;
    const int nwg = gridDim.x * gridDim.y;
    const int flat = blockIdx.y * gridDim.x + blockIdx.x;
    const int q = nwg >> 3;
    const int l_ = (flat & 7) * q + (flat >> 3);
    const int r0 = (l_ / gridDim.x) * 128, c0 = (l_ % gridDim.x) * 128;
    const int srl = lane >> 2;
    const int ssl = ((lane & 3) ^ ((lane >> 3) & 3)) * 8;
    const int frl = lane & 15, kh = lane >> 4;
    const int sw  = (kh ^ ((frl >> 1) & 3)) * 8;
    const int arow0 = (wave >> 1) * 64, bcol0 = (wave & 1) * 64;
    const int w32 = wave * 32;

    f32x4 acc[4][4] = {};

    auto STAGE = [&](int buf, int k0) {
        u16* base = &smem[buf][0];
        u16* As_h = base;        u16* As_l = base + 4096;
        u16* Bs_h = base + 8192; u16* Bs_l = base + 12288;
        const long ga0 = (long)(r0 + w32 + srl) * lda + k0 + ssl;
        gld16(&As_h[w32 * 32],        Agh + ga0);
        gld16(&As_h[(w32 + 16) * 32], Agh + ga0 + 16L * lda);
        gld16(&As_l[w32 * 32],        Agl + ga0);
        gld16(&As_l[(w32 + 16) * 32], Agl + ga0 + 16L * lda);
        const long gb0 = (long)(c0 + w32 + srl) * ldb + k0 + ssl;
        gld16(&Bs_h[w32 * 32],        Bgh + gb0);
        gld16(&Bs_h[(w32 + 16) * 32], Bgh + gb0 + 16L * ldb);
        gld16(&Bs_l[w32 * 32],        Bgl + gb0);
        gld16(&Bs_l[(w32 + 16) * 32], Bgl + gb0 + 16L * ldb);
    };
    auto COMPUTE = [&](int buf) {
        u16* base = &smem[buf][0];
        u16* As_h = base;        u16* As_l = base + 4096;
        u16* Bs_h = base + 8192; u16* Bs_l = base + 12288;
        bf16x8 ah[4], al[4];
#pragma unroll
        for (int f = 0; f < 4; ++f) {
            int ao = (arow0 + f * 16 + frl) * 32 + sw;
            ah[f] = *(const bf16x8*)&As_h[ao];
            al[f] = *(const bf16x8*)&As_l[ao];
        }
#pragma unroll
        for (int j = 0; j < 4; ++j) {
            int bo = (bcol0 + j * 16 + frl) * 32 + sw;
            bf16x8 bh = *(const bf16x8*)&Bs_h[bo];
            bf16x8 bl = *(const bf16x8*)&Bs_l[bo];
#pragma unroll
            for (int i = 0; i < 4; ++i) {
                acc[i][j] = __builtin_amdgcn_mfma_f32_16x16x32_bf16(ah[i], bh, acc[i][j], 0, 0, 0);
                acc[i][j] = __builtin_amdgcn_mfma_f32_16x16x32_bf16(ah[i], bl, acc[i][j], 0, 0, 0);
                acc[i][j] = __builtin_amdgcn_mfma_f32_16x16x32_bf16(al[i], bh, acc[i][j], 0, 0, 0);
            }
        }
    };

    const int NT = K / 32;
    STAGE(0, 0);
#pragma unroll 1
    for (int t = 0; t < NT; t += 2) {
        STAGE(1, (t + 1) * 32);
        asm volatile("s_waitcnt vmcnt(8)" ::: "memory");
        __builtin_amdgcn_sched_barrier(0);
        __builtin_amdgcn_s_barrier();
        __builtin_amdgcn_sched_barrier(0);
        COMPUTE(0);
        __builtin_amdgcn_sched_barrier(0);
        __builtin_amdgcn_s_barrier();
        __builtin_amdgcn_sched_barrier(0);
        if (t + 2 < NT) {
            STAGE(0, (t + 2) * 32);
            asm volatile("s_waitcnt vmcnt(8)" ::: "memory");
        } else {
            asm volatile("s_waitcnt vmcnt(0)" ::: "memory");
        }
        __builtin_amdgcn_sched_barrier(0);
        __builtin_amdgcn_s_barrier();
        __builtin_amdgcn_sched_barrier(0);
        COMPUTE(1);
        __builtin_amdgcn_sched_barrier(0);
        __builtin_amdgcn_s_barrier();
        __builtin_amdgcn_sched_barrier(0);
    }

#pragma unroll
    for (int i = 0; i < 4; ++i)
#pragma unroll
        for (int reg = 0; reg < 4; ++reg) {
            const int r = r0 + arow0 + i * 16 + kh * 4 + reg;
#pragma unroll
            for (int j = 0; j < 4; ++j) {
                const int c = c0 + bcol0 + j * 16 + frl;
                const long o = (long)r * ldc + c;
                float v = acc[i][j][reg];
                if constexpr (EPI == 5) {
#pragma unroll
                    for (int p = 0; p < 9; ++p) v += rwv[(long)r * 9 + p] * bbrv[p * 1024 + c];
                    Cf[o] = v;
                } else if constexpr (EPI == 6) {
                    if (bias) v += bias[c];
                    u16 h, l; split2(v, h, l); Coh[o] = h; Col[o] = l;
                } else {            // EPI 7
                    v = (v + bf2f(CIh[o]) + bf2f(CIl[o])) * rwv[(long)r * 9 + (c >> 8)];
                    u16 h, l; split2(v, h, l); Coh[o] = h; Col[o] = l;
                }
            }
        }
}

// ====== mgemmS: skinny 64x128 tile, 2 waves, for obs/zx (full-GPU grids) ======
template<int EPI>
__global__ __launch_bounds__(128, 2) void mgemmS(
    const u16* __restrict__ Agh, const u16* __restrict__ Agl, int lda,
    const u16* __restrict__ Bgh, const u16* __restrict__ Bgl, int ldb,
    int K,
    float* __restrict__ Cf, int ldc,
    const float* __restrict__ Cinit,
    const float* __restrict__ bias)
{
    __shared__ u16 smem[2][12288];
    const int tid = threadIdx.x, wave = tid >> 6, lane = tid & 63;
    const int nwg = gridDim.x * gridDim.y;
    const int flat = blockIdx.y * gridDim.x + blockIdx.x;
    const int q = nwg >> 3;
    const int l_ = (flat & 7) * q + (flat >> 3);
    const int r0 = (l_ / gridDim.x) * 64, c0 = (l_ % gridDim.x) * 128;
    const int srl = lane >> 2;
    const int ssl = ((lane & 3) ^ ((lane >> 3) & 3)) * 8;
    const int frl = lane & 15, kh = lane >> 4;
    const int sw  = (kh ^ ((frl >> 1) & 3)) * 8;
    const int w32 = wave * 32, w64 = wave * 64;

    f32x4 acc[4][4] = {};

    auto STAGE = [&](int buf, int k0) {
        u16* Ash = &smem[buf][0];
        u16* Asl = &smem[buf][2048];
        u16* Bsh = &smem[buf][4096];
        u16* Bsl = &smem[buf][8192];
        const long ga = (long)(r0 + w32 + srl) * lda + k0 + ssl;
        gld16(&Ash[w32 * 32],        Agh + ga);
        gld16(&Ash[(w32 + 16) * 32], Agh + ga + 16L * lda);
        gld16(&Asl[w32 * 32],        Agl + ga);
        gld16(&Asl[(w32 + 16) * 32], Agl + ga + 16L * lda);
        const long gb = (long)(c0 + w64 + srl) * ldb + k0 + ssl;
        gld16(&Bsh[w64 * 32],        Bgh + gb);
        gld16(&Bsh[(w64 + 16) * 32], Bgh + gb + 16L * ldb);
        gld16(&Bsh[(w64 + 32) * 32], Bgh + gb + 32L * ldb);
        gld16(&Bsh[(w64 + 48) * 32], Bgh + gb + 48L * ldb);
        gld16(&Bsl[w64 * 32],        Bgl + gb);
        gld16(&Bsl[(w64 + 16) * 32], Bgl + gb + 16L * ldb);
        gld16(&Bsl[(w64 + 32) * 32], Bgl + gb + 32L * ldb);
        gld16(&Bsl[(w64 + 48) * 32], Bgl + gb + 48L * ldb);
    };
    auto COMPUTE = [&](int buf) {
        u16* Ash = &smem[buf][0];
        u16* Asl = &smem[buf][2048];
        u16* Bsh = &smem[buf][4096];
        u16* Bsl = &smem[buf][8192];
        bf16x8 ah[4], al[4];
#pragma unroll
        for (int f = 0; f < 4; ++f) {
            int ao = (f * 16 + frl) * 32 + sw;
            ah[f] = *(const bf16x8*)&Ash[ao];
            al[f] = *(const bf16x8*)&Asl[ao];
        }
#pragma unroll
        for (int j = 0; j < 4; ++j) {
            int bo = (w64 + j * 16 + frl) * 32 + sw;
            bf16x8 bh = *(const bf16x8*)&Bsh[bo];
            bf16x8 bl = *(const bf16x8*)&Bsl[bo];
#pragma unroll
            for (int i = 0; i < 4; ++i) {
                acc[i][j] = __builtin_amdgcn_mfma_f32_16x16x32_bf16(ah[i], bh, acc[i][j], 0, 0, 0);
                acc[i][j] = __builtin_amdgcn_mfma_f32_16x16x32_bf16(ah[i], bl, acc[i][j], 0, 0, 0);
                acc[i][j] = __builtin_amdgcn_mfma_f32_16x16x32_bf16(al[i], bh, acc[i][j], 0, 0, 0);
            }
        }
    };

    const int NT = K / 32;
    STAGE(0, 0);
#pragma unroll 1
    for (int t = 0; t < NT; t += 2) {
        STAGE(1, (t + 1) * 32);
        asm volatile("s_waitcnt vmcnt(12)" ::: "memory");
        __builtin_amdgcn_sched_barrier(0);
        __builtin_amdgcn_s_barrier();
        __builtin_amdgcn_sched_barrier(0);
        COMPUTE(0);
        __builtin_amdgcn_sched_barrier(0);
        __builtin_amdgcn_s_barrier();
        __builtin_amdgcn_sched_barrier(0);
        if (t + 2 < NT) {
            STAGE(0, (t + 2) * 32);
            asm volatile("s_waitcnt vmcnt(12)" ::: "memory");
        } else {
            asm volatile("s_waitcnt vmcnt(0)" ::: "memory");
        }
        __builtin_amdgcn_sched_barrier(0);
        __builtin_amdgcn_s_barrier();
        __builtin_amdgcn_sched_barrier(0);
        COMPUTE(1);
        __builtin_amdgcn_sched_barrier(0);
        __builtin_amdgcn_s_barrier();
        __builtin_amdgcn_sched_barrier(0);
    }

#pragma unroll
    for (int i = 0; i < 4; ++i)
#pragma unroll
        for (int reg = 0; reg < 4; ++reg) {
            const int r = r0 + i * 16 + kh * 4 + reg;
#pragma unroll
            for (int j = 0; j < 4; ++j) {
                const int c = c0 + w64 + j * 16 + frl;
                const long o = (long)r * ldc + c;
                float v = acc[i][j][reg];
                if constexpr (EPI == 0) Cf[o] = v + bias[c];
                else                    Cf[o] = tanhf(v + Cinit[o]);
            }
        }
}

// ====== final routing: bucketed K=256 GEMM with indirect rows ======
__global__ void bucket_k(const int* __restrict__ pstar, int* __restrict__ cnt,
                         int* __restrict__ perm)
{
    int n = blockIdx.x * 256 + threadIdx.x;
    if (n >= Nn) return;
    int p = pstar[n];
    int slot = atomicAdd(&cnt[p], 1);
    if (slot < CAP) perm[p * CAP + slot] = n;
}

__global__ __launch_bounds__(256, 2) void mgemm_fin(
    const u16* __restrict__ hph, const u16* __restrict__ hpl,
    const u16* __restrict__ Wbth, const u16* __restrict__ Wbtl,
    const int* __restrict__ perm, const int* __restrict__ cnt,
    const float* __restrict__ rwS, const float* __restrict__ bbr,
    float* __restrict__ craw)
{
    __shared__ u16 smem[2][16384];
    const int tid = threadIdx.x, wave = tid >> 6, lane = tid & 63;
    const int p = blockIdx.y >> 5;
    const int rb0 = (blockIdx.y & 31) * 128;
    const int cntp = cnt[p];
    if (rb0 >= cntp) return;
    const int c0 = blockIdx.x * 128;
    const int pbase = p * 256;
    const int srl = lane >> 2;
    const int ssl = ((lane & 3) ^ ((lane >> 3) & 3)) * 8;
    const int frl = lane & 15, kh = lane >> 4;
    const int sw  = (kh ^ ((frl >> 1) & 3)) * 8;
    const int arow0 = (wave >> 1) * 64, bcol0 = (wave & 1) * 64;
    const int w32 = wave * 32;
    const int tok0 = perm[p * CAP + rb0 + w32 + srl];
    const int tok1 = perm[p * CAP + rb0 + w32 + 16 + srl];

    f32x4 acc[4][4] = {};

    auto STAGE = [&](int buf, int k0) {
        u16* base = &smem[buf][0];
        u16* As_h = base;        u16* As_l = base + 4096;
        u16* Bs_h = base + 8192; u16* Bs_l = base + 12288;
        const long ga0 = (long)tok0 * Kc + pbase + k0 + ssl;
        const long ga1 = (long)tok1 * Kc + pbase + k0 + ssl;
        gld16(&As_h[w32 * 32],        hph + ga0);
        gld16(&As_h[(w32 + 16) * 32], hph + ga1);
        gld16(&As_l[w32 * 32],        hpl + ga0);
        gld16(&As_l[(w32 + 16) * 32], hpl + ga1);
        const long gb0 = (long)(c0 + w32 + srl) * Kc + pbase + k0 + ssl;
        gld16(&Bs_h[w32 * 32],        Wbth + gb0);
        gld16(&Bs_h[(w32 + 16) * 32], Wbth + gb0 + 16L * Kc);
        gld16(&Bs_l[w32 * 32],        Wbtl + gb0);
        gld16(&Bs_l[(w32 + 16) * 32], Wbtl + gb0 + 16L * Kc);
    };
    auto COMPUTE = [&](int buf) {
        u16* base = &smem[buf][0];
        u16* As_h = base;        u16* As_l = base + 4096;
        u16* Bs_h = base + 8192; u16* Bs_l = base + 12288;
        bf16x8 ah[4], al[4];
#pragma unroll
        for (int f = 0; f < 4; ++f) {
            int ao = (arow0 + f * 16 + frl) * 32 + sw;
            ah[f] = *(const bf16x8*)&As_h[ao];
            al[f] = *(const bf16x8*)&As_l[ao];
        }
#pragma unroll
        for (int j = 0; j < 4; ++j) {
            int bo = (bcol0 + j * 16 + frl) * 32 + sw;
            bf16x8 bh = *(const bf16x8*)&Bs_h[bo];
            bf16x8 bl = *(const bf16x8*)&Bs_l[bo];
#pragma unroll
            for (int i = 0; i < 4; ++i) {
                acc[i][j] = __builtin_amdgcn_mfma_f32_16x16x32_bf16(ah[i], bh, acc[i][j], 0, 0, 0);
                acc[i][j] = __builtin_amdgcn_mfma_f32_16x16x32_bf16(ah[i], bl, acc[i][j], 0, 0, 0);
                acc[i][j] = __builtin_amdgcn_mfma_f32_16x16x32_bf16(al[i], bh, acc[i][j], 0, 0, 0);
            }
        }
    };

    STAGE(0, 0);
#pragma unroll 1
    for (int t = 0; t < 8; t += 2) {
        STAGE(1, (t + 1) * 32);
        asm volatile("s_waitcnt vmcnt(8)" ::: "memory");
        __builtin_amdgcn_sched_barrier(0);
        __builtin_amdgcn_s_barrier();
        __builtin_amdgcn_sched_barrier(0);
        COMPUTE(0);
        __builtin_amdgcn_sched_barrier(0);
        __builtin_amdgcn_s_barrier();
        __builtin_amdgcn_sched_barrier(0);
        if (t + 2 < 8) {
            STAGE(0, (t + 2) * 32);
            asm volatile("s_waitcnt vmcnt(8)" ::: "memory");
        } else {
            asm volatile("s_waitcnt vmcnt(0)" ::: "memory");
        }
        __builtin_amdgcn_sched_barrier(0);
        __builtin_amdgcn_s_barrier();
        __builtin_amdgcn_sched_barrier(0);
        COMPUTE(1);
        __builtin_amdgcn_sched_barrier(0);
        __builtin_amdgcn_s_barrier();
        __builtin_amdgcn_sched_barrier(0);
    }

#pragma unroll
    for (int i = 0; i < 4; ++i)
#pragma unroll
        for (int reg = 0; reg < 4; ++reg) {
            const int gr = rb0 + arow0 + i * 16 + kh * 4 + reg;
            if (gr < cntp) {
                const int tokr = perm[p * CAP + gr];
                const float w = 1.f / rwS[(long)tokr * Pp + p];
#pragma unroll
                for (int j = 0; j < 4; ++j) {
                    const int c = c0 + bcol0 + j * 16 + frl;
                    craw[(long)tokr * Dd + c] = acc[i][j][reg] * w + bbr[p * 1024 + c];
                }
            }
        }
}

// ---------------- logits: wave-parallel (8 lanes per p, shfl reduce) ----------
__global__ void logits_k(const float* __restrict__ h, const float* __restrict__ W2r,
                         const float* __restrict__ b2r, const float* __restrict__ gum,
                         float* __restrict__ rwA, int* __restrict__ pstar, int hard)
{
    __shared__ float hs[Mm];
    __shared__ float lg[16];
    int n = blockIdx.x;
    int lane = threadIdx.x;
    for (int i = lane; i < Mm; i += 64) hs[i] = h[(long)n * Mm + i];
    __syncthreads();
    // p = 0..7: 8 lanes each
    {
        int p = lane >> 3, i = lane & 7;
        float acc = 0.f;
        for (int m = i; m < Mm; m += 8) acc += hs[m] * W2r[m * Pp + p];
        acc += __shfl_xor(acc, 1);
        acc += __shfl_xor(acc, 2);
        acc += __shfl_xor(acc, 4);
        if (i == 0) lg[p] = acc + b2r[p] + gum[(long)n * Pp + p];
    }
    // p = 8: lanes 0..7
    if (lane < 8) {
        float acc = 0.f;
        for (int m = lane; m < Mm; m += 8) acc += hs[m] * W2r[m * Pp + 8];
        acc += __shfl_xor(acc, 1);
        acc += __shfl_xor(acc, 2);
        acc += __shfl_xor(acc, 4);
        if (lane == 0) lg[8] = acc + b2r[8] + gum[(long)n * Pp + 8];
    }
    __syncthreads();
    if (lane == 0) {
        float mx = lg[0]; int am = 0;
#pragma unroll
        for (int p = 1; p < Pp; ++p) if (lg[p] > mx) { mx = lg[p]; am = p; }
        if (hard) {
            pstar[n] = am;
        } else {
            float e[Pp]; float ssum = 0.f;
#pragma unroll
            for (int p = 0; p < Pp; ++p) { e[p] = expf(lg[p] - mx); ssum += e[p]; }
#pragma unroll
            for (int p = 0; p < Pp; ++p) rwA[(long)n * Pp + p] = e[p] / ssum;
        }
    }
}

// ---------------- mod-phase RMS norm (group = d % 7), padded LDS ----------------
template<int INSPLIT, int OUTSPLIT>
__global__ void norm_k(const float* __restrict__ in,
                       const u16* __restrict__ inh, const u16* __restrict__ inl,
                       const float* __restrict__ add, const float* __restrict__ g,
                       float* __restrict__ outf, u16* __restrict__ oh, u16* __restrict__ ol)
{
    __shared__ float sb[256][9];     // stride 9: coprime with 32 banks -> no conflict
    __shared__ float dn[8];
    int n = blockIdx.x;
    int t = threadIdx.x;
    float v[4];
#pragma unroll
    for (int j = 0; j < 7; ++j) sb[t][j] = 0.f;
#pragma unroll
    for (int i = 0; i < 4; ++i) {
        int d = t + i * 256;
        long o = (long)n * Dd + d;
        float xv = INSPLIT ? (bf2f(inh[o]) + bf2f(inl[o])) : in[o];
        if (add) xv += add[o];
        v[i] = xv;
        sb[t][d % 7] += xv * xv;
    }
    __syncthreads();
    for (int st = 128; st >= 1; st >>= 1) {
        if (t < st) {
#pragma unroll
            for (int j = 0; j < 7; ++j) sb[t][j] += sb[t + st][j];
        }
        __syncthreads();
    }
    if (t < 7) {
        const float cnt = (t < 2) ? 147.f : 146.f;
        dn[t] = 1.f / sqrtf(sb[0][t] / cnt + EPSf);
    }
    __syncthreads();
#pragma unroll
    for (int i = 0; i < 4; ++i) {
        int d = t + i * 256;
        long o = (long)n * Dd + d;
        float ov = v[i] * dn[d % 7] * g[d];
        if (OUTSPLIT) { u16 h, l; split2(ov, h, l); oh[o] = h; ol[o] = l; }
        else outf[o] = ov;
    }
}

static inline int cdiv(long a, long b) { return (int)((a + b - 1) / b); }
static inline size_t al256(size_t b) { return (b + 255) & ~(size_t)255; }

extern "C" void kernel_launch(void* const* d_in, const int* in_sizes, int n_in,
                              void* d_out, int out_size, void* d_ws, size_t ws_size,
                              hipStream_t stream)
{
    const float* x    = (const float*)d_in[0];
    const float* gum  = (const float*)d_in[1];
    const float* mw   = (const float*)d_in[2];
    const float* W1   = (const float*)d_in[3];
    const float* b1   = (const float*)d_in[4];
    const float* th1  = (const float*)d_in[5];
    const float* W2   = (const float*)d_in[6];
    const float* b2   = (const float*)d_in[7];
    const float* th2  = (const float*)d_in[8];
    const float* Wa   = (const float*)d_in[9];
    const float* ba   = (const float*)d_in[10];
    const float* tha  = (const float*)d_in[11];
    const float* Wb   = (const float*)d_in[12];
    const float* bbv  = (const float*)d_in[13];
    const float* thb  = (const float*)d_in[14];
    const float* tW   = (const float*)d_in[15];
    const float* tb   = (const float*)d_in[16];
    const float* tth  = (const float*)d_in[17];
    const float* gnorm = (const float*)d_in[18];

    char* cur = (char*)d_ws;
    auto alloc = [&](size_t bytes) -> void* { void* r = cur; cur += al256(bytes); return r; };

    void* region = alloc((size_t)Nn * Dd * 4);   // craw f32 == hbuf f32 == xm split
    float* zx   = (float*)alloc((size_t)Nn * Mm * 4);
    float* rwS  = (float*)alloc((size_t)Nn * Pp * 4);
    u16* colh = (u16*)alloc((size_t)Nn * Dd * 2);
    u16* coll = (u16*)alloc((size_t)Nn * Dd * 2);
    u16* hph  = (u16*)alloc((size_t)Nn * Kc * 2);
    u16* hpl  = (u16*)alloc((size_t)Nn * Kc * 2);
    u16* W1th = (u16*)alloc(256 * 2048 * 2);
    u16* W1tl = (u16*)alloc(256 * 2048 * 2);
    u16* Wath = (u16*)alloc((size_t)Kc * 1024 * 2);
    u16* Watl = (u16*)alloc((size_t)Kc * 1024 * 2);
    u16* Wbth = (u16*)alloc((size_t)1024 * Kc * 2);
    u16* Wbtl = (u16*)alloc((size_t)1024 * Kc * 2);
    u16* zxah  = (u16*)alloc((size_t)Nn * Kc * 2);
    u16* zxal  = (u16*)alloc((size_t)Nn * Kc * 2);
    u16* tWtTh = (u16*)alloc((size_t)1024 * 1024 * 2);
    u16* tWtTl = (u16*)alloc((size_t)1024 * 1024 * 2);
    u16* Wfath = (u16*)alloc((size_t)Kc * 1024 * 2);
    u16* Wfatl = (u16*)alloc((size_t)Kc * 1024 * 2);
    float* W2r  = (float*)alloc(256 * 9 * 4);
    float* b1r  = (float*)alloc(256 * 4);
    float* b2r  = (float*)alloc(64);
    float* bac  = (float*)alloc(Kc * 4);
    float* bac2 = (float*)alloc(Kc * 4);
    float* bbr  = (float*)alloc(Pp * 1024 * 4);
    float* tbr  = (float*)alloc(1024 * 4);
    int* pstar = (int*)alloc(Nn * 4);
    int* perm  = (int*)alloc((size_t)Pp * CAP * 4);
    int* cnt   = (int*)alloc(Pp * 4);
    if ((size_t)(cur - (char*)d_ws) > ws_size) return;

    float* hbuf = (float*)region;
    float* craw = (float*)region;
    u16* xmh = (u16*)region;
    u16* xml = xmh + (size_t)Nn * Dd;
    float* out0 = (float*)d_out;
    float* out1 = out0 + (long)Nn * Dd;

    // ---- prep ----
    splitW1_k<<<2048, 256, 0, stream>>>(W1, th1, W1th, W1tl);
    splitWa_k<<<cdiv((long)Kc * 1024, 256), 256, 0, stream>>>(Wa, tha, Wath, Watl);
    splitWb_k<<<cdiv((long)1024 * Kc, 256), 256, 0, stream>>>(Wb, thb, Wbth, Wbtl);
    rotcopy_k<<<cdiv(256L * 9, 256), 256, 0, stream>>>(W2, W2r, 256, 9, th2, 1);
    rotcopy_k<<<1, 256, 0, stream>>>(b1, b1r, 1, 256, th1, 1);
    rotcopy_k<<<1, 256, 0, stream>>>(b2, b2r, 1, 9, th2, 1);
    rotcopy_k<<<cdiv((long)Pp * Mm, 256), 256, 0, stream>>>(ba, bac, 1, 256, tha, 9);
    rotcopy_k<<<cdiv((long)Pp * 1024, 256), 256, 0, stream>>>(bbv, bbr, 1, 1024, thb, 9);
    rotcopy_k<<<cdiv(1024L, 256), 256, 0, stream>>>(tb, tbr, 1, 1024, tth, 1);
    splitTWT_k<<<4096, 256, 0, stream>>>(tW, tth, tWtTh, tWtTl);
    hipMemsetAsync(perm, 0, (size_t)Pp * CAP * 4, stream);
    hipMemsetAsync(cnt, 0, Pp * 4, stream);

    // Wfat[pm,e] = sum_d Wat[pm,d] * tWtT[e,d]
    mgemm<6><<<dim3(8, 18), 256, 0, stream>>>(
        Wath, Watl, 1024, tWtTh, tWtTl, 1024, 1024,
        nullptr, Wfath, Wfatl, 1024, nullptr, nullptr, nullptr, nullptr, nullptr);
    bac2_k<<<Kc, 256, 0, stream>>>(bac, tbr, Wath, Watl, bac2);

    mixer_k<<<Nn * Dd / 4 / 256, 256, 0, stream>>>(x, mw, xmh, xml);
    // zx = xm @ W1_top + b1r  (skinny, 256 blocks)
    mgemmS<0><<<dim3(2, 128), 128, 0, stream>>>(
        xmh, xml, 1024, W1th, W1tl, 2048, 1024, zx, 256, nullptr, b1r);
    // zxa = xm @ Wat + bac2   (split out) — before tanh clobbers xm
    mgemm<6><<<dim3(18, 64), 256, 0, stream>>>(
        xmh, xml, 1024, Wath, Watl, 1024, 1024,
        nullptr, zxah, zxal, Kc, nullptr, nullptr, bac2, nullptr, nullptr);

    for (int t = 0; t < 3; ++t) {
        if (t == 0) {
            tanh_k<<<cdiv((long)Nn * Mm, 256), 256, 0, stream>>>(zx, hbuf, Nn * Mm);
        } else {
            mgemmS<1><<<dim3(2, 128), 128, 0, stream>>>(
                colh, coll, 1024, W1th + 1024, W1tl + 1024, 2048, 1024,
                hbuf, 256, zx, nullptr);
        }
        logits_k<<<Nn, 64, 0, stream>>>(hbuf, W2r, b2r, gum + (long)t * Nn * Pp,
                                        rwS, nullptr, 0);
        if (t == 0) {
            hp0_k<<<cdiv((long)Nn * Kc / 4, 256), 256, 0, stream>>>(zxah, zxal, rwS, hph, hpl);
        } else {
            // hp = (zxa + col @ Wfat) * rw
            mgemm<7><<<dim3(18, 64), 256, 0, stream>>>(
                colh, coll, 1024, Wfath, Wfatl, 1024, 1024,
                nullptr, hph, hpl, Kc, zxah, zxal, nullptr, rwS, nullptr);
        }
        // craw = hp @ Wbt + sum_p rw_p bbr_p
        mgemm<5><<<dim3(8, 64), 256, 0, stream>>>(
            hph, hpl, Kc, Wbth, Wbtl, Kc, Kc,
            craw, nullptr, nullptr, 1024, nullptr, nullptr, nullptr, rwS, bbr);
        norm_k<0, 1><<<Nn, 256, 0, stream>>>(craw, nullptr, nullptr, nullptr, gnorm,
                                             nullptr, colh, coll);
    }

    // ---- final hard routing (bucketed) ----
    mgemmS<1><<<dim3(2, 128), 128, 0, stream>>>(
        colh, coll, 1024, W1th + 1024, W1tl + 1024, 2048, 1024,
        hbuf, 256, zx, nullptr);
    logits_k<<<Nn, 64, 0, stream>>>(hbuf, W2r, b2r, gum + 3L * Nn * Pp,
                                    nullptr, pstar, 1);
    bucket_k<<<32, 256, 0, stream>>>(pstar, cnt, perm);
    mgemm_fin<<<dim3(8, Pp * 32), 256, 0, stream>>>(
        hph, hpl, Wbth, Wbtl, perm, cnt, rwS, bbr, craw);
    // out0 = norm(x + fc_raw); out1 = norm(collapsed)
    norm_k<0, 0><<<Nn, 256, 0, stream>>>(craw, nullptr, nullptr, x, gnorm, out0, nullptr, nullptr);
    norm_k<1, 0><<<Nn, 256, 0, stream>>>(nullptr, colh, coll, nullptr, gnorm, out1, nullptr, nullptr);
}